// Round 8
// baseline (113.145 us; speedup 1.0000x reference)
//
#include <hip/hip_runtime.h>
#include <cstdint>
#include <cstddef>

#define L_SEQ 2048
#define E_DIM 512
#define B_SZ 2
#define WIN 64
#define SCALE_QK 0.044194173824159216f  // 1/sqrt(512)

typedef __attribute__((ext_vector_type(8))) short short8;
typedef __attribute__((ext_vector_type(4))) float floatx4;

__device__ __forceinline__ unsigned short f2bf(float f) {
    unsigned int u = __float_as_uint(f);
    u += 0x7FFFu + ((u >> 16) & 1u);
    return (unsigned short)(u >> 16);
}

// ---------------- fp32 -> bf16 conversion of x, Wq, Wk, Wv ----------------
__global__ __launch_bounds__(256) void cvt_kernel(
    const float* __restrict__ x, const float* __restrict__ wq,
    const float* __restrict__ wk, const float* __restrict__ wv,
    unsigned short* __restrict__ xb, unsigned short* __restrict__ wb)
{
    long i = (long)blockIdx.x * 256 + threadIdx.x;   // 0 .. 720895
    const float* src;
    unsigned short* dst;
    long off;
    if (i < 524288) {
        src = x; dst = xb; off = i;
    } else {
        long j = i - 524288;
        int w = (int)(j >> 16);
        off = j & 65535;
        src = (w == 0) ? wq : ((w == 1) ? wk : wv);
        dst = wb + (long)w * 262144;
    }
    float4 f = ((const float4*)src)[off];
    ushort4 o;
    o.x = f2bf(f.x); o.y = f2bf(f.y); o.z = f2bf(f.z); o.w = f2bf(f.w);
    ((ushort4*)dst)[off] = o;
}

// ---------------- QKV projection: 64x64 tile, BK=64, reg double-buffer (R5/R7 winner) ----------------
// C[m,n] = sum_k X[m,k] W[n,k] + bias[n].  Outputs bf16, coalesced via LDS transpose.
// z==0 -> q[m][n], z==1 -> k[m][n], z==2 -> vT[n][m] (token-contiguous rows).
// grid (64,8,3) = 1536 blocks = 6 blocks/CU.
#define ALD 72   // LDS row stride (bf16): 36 dw -> 2-way conflicts only per 16-lane phase
__global__ __launch_bounds__(256) void qkv_gemm(
    const unsigned short* __restrict__ xb,   // 4096 x 512
    const unsigned short* __restrict__ wb,   // 3 x (512 x 512), (N,K)
    const float* __restrict__ bq, const float* __restrict__ bk, const float* __restrict__ bv,
    unsigned short* __restrict__ q, unsigned short* __restrict__ k,
    unsigned short* __restrict__ vt)
{
    __shared__ __align__(16) unsigned short As[64 * ALD];   // 9216 B (aliased by epilogue)
    __shared__ __align__(16) unsigned short Bs[64 * ALD];

    const int t = threadIdx.x;
    const int w = t >> 6, l = t & 63;
    const int m0 = blockIdx.x * 64, n0 = blockIdx.y * 64, z = blockIdx.z;
    const unsigned short* W = wb + (size_t)z * 262144;
    const float* bias = (z == 0) ? bq : ((z == 1) ? bk : bv);

    floatx4 acc[2][2] = {};
    const int wm = (w >> 1) * 32, wn = (w & 1) * 32;
    const int fr = l & 15, fq = l >> 4, fk = fq * 8;

    const int srow = t >> 2, scol = (t & 3) * 16;
    const unsigned short* gA = xb + (size_t)(m0 + srow) * 512 + scol;
    const unsigned short* gB = W  + (size_t)(n0 + srow) * 512 + scol;

    uint4 ra0 = *(const uint4*)(gA);     uint4 ra1 = *(const uint4*)(gA + 8);
    uint4 rb0 = *(const uint4*)(gB);     uint4 rb1 = *(const uint4*)(gB + 8);

    for (int it = 0; it < 8; it++) {
        *(uint4*)&As[srow * ALD + scol]     = ra0;
        *(uint4*)&As[srow * ALD + scol + 8] = ra1;
        *(uint4*)&Bs[srow * ALD + scol]     = rb0;
        *(uint4*)&Bs[srow * ALD + scol + 8] = rb1;
        __syncthreads();
        if (it < 7) {                       // prefetch next K-slice; overlaps compute below
            int kk = (it + 1) * 64;
            ra0 = *(const uint4*)(gA + kk); ra1 = *(const uint4*)(gA + kk + 8);
            rb0 = *(const uint4*)(gB + kk); rb1 = *(const uint4*)(gB + kk + 8);
        }
        short8 a[2][2], bf[2][2];
#pragma unroll
        for (int i = 0; i < 2; i++)
#pragma unroll
            for (int kh = 0; kh < 2; kh++)
                a[i][kh] = *(const short8*)&As[(wm + i * 16 + fr) * ALD + kh * 32 + fk];
#pragma unroll
        for (int j = 0; j < 2; j++)
#pragma unroll
            for (int kh = 0; kh < 2; kh++)
                bf[j][kh] = *(const short8*)&Bs[(wn + j * 16 + fr) * ALD + kh * 32 + fk];
#pragma unroll
        for (int kh = 0; kh < 2; kh++)
#pragma unroll
            for (int i = 0; i < 2; i++)
#pragma unroll
                for (int j = 0; j < 2; j++)
                    acc[i][j] = __builtin_amdgcn_mfma_f32_16x16x32_bf16(a[i][kh], bf[j][kh], acc[i][j], 0, 0, 0);
        __syncthreads();
    }

    // epilogue: frags (C/D: col=lane&15, row=(lane>>4)*4+reg) -> LDS tile -> coalesced stores
    unsigned short* Tl = As;   // 64 x ALD alias
    float bv_[2];
#pragma unroll
    for (int j = 0; j < 2; j++) bv_[j] = bias[n0 + wn + j * 16 + fr];

    if (z < 2) {
#pragma unroll
        for (int i = 0; i < 2; i++)
#pragma unroll
            for (int j = 0; j < 2; j++)
#pragma unroll
                for (int r = 0; r < 4; r++)
                    Tl[(wm + i * 16 + fq * 4 + r) * ALD + wn + j * 16 + fr] =
                        f2bf(acc[i][j][r] + bv_[j]);
    } else {
#pragma unroll
        for (int i = 0; i < 2; i++)
#pragma unroll
            for (int j = 0; j < 2; j++)
#pragma unroll
                for (int r = 0; r < 4; r++)
                    Tl[(wn + j * 16 + fr) * ALD + wm + i * 16 + fq * 4 + r] =
                        f2bf(acc[i][j][r] + bv_[j]);
    }
    __syncthreads();

    const int tr = t >> 2, tc = (t & 3) * 16;
    uint4 v0 = *(const uint4*)&Tl[tr * ALD + tc];
    uint4 v1 = *(const uint4*)&Tl[tr * ALD + tc + 8];
    if (z < 2) {
        unsigned short* out = (z == 0) ? q : k;
        *(uint4*)&out[(size_t)(m0 + tr) * 512 + n0 + tc]     = v0;
        *(uint4*)&out[(size_t)(m0 + tr) * 512 + n0 + tc + 8] = v1;
    } else {
        *(uint4*)&vt[(size_t)(n0 + tr) * 4096 + m0 + tc]     = v0;
        *(uint4*)&vt[(size_t)(n0 + tr) * 4096 + m0 + tc + 8] = v1;
    }
}

// ---------------- scores: S[16x16] per one-wave block, direct frag loads ----------------
// grid (128 Qtiles, 9 ntiles, 2 b), 64 threads. S fp32 [4096][160], cols 0..143 written.
__global__ __launch_bounds__(64) void scores_kernel(
    const unsigned short* __restrict__ qb, const unsigned short* __restrict__ kb,
    float* __restrict__ S)
{
    const int l = threadIdx.x;
    const int fr = l & 15, fq = l >> 4;
    const int Q0 = blockIdx.x * 16;
    const int nt = blockIdx.y;
    const int b  = blockIdx.z;
    const int R0 = Q0 - WIN;
    const int tok = R0 + nt * 16 + fr;
    const bool kvalid = (tok >= 0) && (tok < L_SEQ);

    const unsigned short* qrow = qb + (size_t)(b * L_SEQ + Q0 + fr) * 512 + fq * 8;
    const unsigned short* krow = kb + (size_t)(b * L_SEQ) * 512 + (size_t)tok * 512 + fq * 8;

    floatx4 acc = {};
#pragma unroll
    for (int ks = 0; ks < 16; ks++) {
        short8 a = *(const short8*)(qrow + ks * 32);
        short8 bfr = {};
        if (kvalid) bfr = *(const short8*)(krow + ks * 32);
        acc = __builtin_amdgcn_mfma_f32_16x16x32_bf16(a, bfr, acc, 0, 0, 0);
    }

    const int jg = nt * 16 + fr;
    float* Srow = S + (size_t)(b * L_SEQ + Q0) * 160 + jg;
#pragma unroll
    for (int r = 0; r < 4; r++) {
        int qq = fq * 4 + r;
        bool valid = (jg >= qq) && (jg <= qq + 128) && kvalid;
        Srow[(size_t)qq * 160] = valid ? acc[r] * SCALE_QK : -1e30f;
    }
}

// ---------------- softmax: one wave per row, S fp32 -> P bf16 [4096][160] ----------------
__global__ __launch_bounds__(256) void softmax_kernel(
    const float* __restrict__ S, unsigned short* __restrict__ P)
{
    const int t = threadIdx.x;
    const int row = blockIdx.x * 4 + (t >> 6);
    const int l = t & 63;
    const float* Sr = S + (size_t)row * 160;
    float s1 = Sr[l], s2 = Sr[64 + l];
    float s3 = (l < 16) ? Sr[128 + l] : -1e30f;
    float m = fmaxf(fmaxf(s1, s2), s3);
#pragma unroll
    for (int d = 32; d >= 1; d >>= 1) m = fmaxf(m, __shfl_xor(m, d));
    float e1 = __expf(s1 - m), e2 = __expf(s2 - m);
    float e3 = (l < 16) ? __expf(s3 - m) : 0.f;
    float sum = e1 + e2 + e3;
#pragma unroll
    for (int d = 32; d >= 1; d >>= 1) sum += __shfl_xor(sum, d);
    float inv = 1.f / sum;
    unsigned short* Pr = P + (size_t)row * 160;
    Pr[l] = f2bf(e1 * inv);
    Pr[64 + l] = f2bf(e2 * inv);
    if (l < 16) Pr[128 + l] = f2bf(e3 * inv);
    else if (l < 32) Pr[128 + l] = 0;   // zero K-pad cols 144..159
}

// ---------------- pv: out[16q x 64e] per one-wave block, P-direct A-frags ----------------
// grid (128 Qtiles, 8 e-quads, 2 b), 64 threads. P bf16 A-frags + vT B-frags from global.
__global__ __launch_bounds__(64) void pv_kernel(
    const unsigned short* __restrict__ P, const unsigned short* __restrict__ vt,
    float* __restrict__ out)
{
    const int l = threadIdx.x;
    const int fr = l & 15, fq = l >> 4;
    const int Q0 = blockIdx.x * 16;
    const int EC = blockIdx.y * 64;
    const int b  = blockIdx.z;
    const int R0 = Q0 - WIN;

    const unsigned short* Prow = P + (size_t)(b * L_SEQ + Q0 + fr) * 160 + fq * 8;

    short8 a[5];
#pragma unroll
    for (int ks = 0; ks < 5; ks++) a[ks] = *(const short8*)(Prow + ks * 32);

    floatx4 oa[4] = {};
#pragma unroll
    for (int ks = 0; ks < 5; ks++) {
        int tok0 = R0 + ks * 32 + fq * 8;                 // mod-8 aligned granule
        bool tv = (tok0 >= 0) && (tok0 < L_SEQ);
#pragma unroll
        for (int et = 0; et < 4; et++) {
            short8 bfr = {};
            if (tv) bfr = *(const short8*)&vt[(size_t)(EC + et * 16 + fr) * 4096 + b * L_SEQ + tok0];
            oa[et] = __builtin_amdgcn_mfma_f32_16x16x32_bf16(a[ks], bfr, oa[et], 0, 0, 0);
        }
    }

    float* op = out + (size_t)b * L_SEQ * E_DIM;
#pragma unroll
    for (int et = 0; et < 4; et++)
#pragma unroll
        for (int r = 0; r < 4; r++)
            op[(size_t)(Q0 + fq * 4 + r) * 512 + EC + et * 16 + fr] = oa[et][r];
}

// ---------------- launch ----------------
extern "C" void kernel_launch(void* const* d_in, const int* in_sizes, int n_in,
                              void* d_out, int out_size, void* d_ws, size_t ws_size,
                              hipStream_t stream)
{
    const float* x  = (const float*)d_in[0];
    const float* Wq = (const float*)d_in[1];
    const float* bq = (const float*)d_in[2];
    const float* Wk = (const float*)d_in[3];
    const float* bk = (const float*)d_in[4];
    const float* Wv = (const float*)d_in[5];
    const float* bv = (const float*)d_in[6];
    float* out = (float*)d_out;

    char* ws = (char*)d_ws;
    unsigned short* qb = (unsigned short*)(ws);                  // 4 MB bf16 q
    unsigned short* kb = (unsigned short*)(ws + 4194304);        // 4 MB bf16 k
    unsigned short* vt = (unsigned short*)(ws + 8388608);        // 4 MB bf16 v^T [e][tok]
    unsigned short* xb = (unsigned short*)(ws + 12582912);       // 4 MB bf16 x
    unsigned short* wb = (unsigned short*)(ws + 16777216);       // 1.5 MB bf16 W
    float*          S  = (float*)(ws + 18350080);                // 2.62 MB fp32 [4096][160]
    unsigned short* P  = (unsigned short*)(ws + 20971520);       // 1.31 MB bf16 [4096][160]

    cvt_kernel<<<2816, 256, 0, stream>>>(x, Wq, Wk, Wv, xb, wb);
    qkv_gemm<<<dim3(64, 8, 3), 256, 0, stream>>>(xb, wb, bq, bk, bv, qb, kb, vt);
    scores_kernel<<<dim3(128, 9, 2), 64, 0, stream>>>(qb, kb, S);
    softmax_kernel<<<1024, 256, 0, stream>>>(S, P);
    pv_kernel<<<dim3(128, 8, 2), 64, 0, stream>>>(P, vt, out);
}

// Round 9
// 111.847 us; speedup vs baseline: 1.0116x; 1.0116x over previous
//
#include <hip/hip_runtime.h>
#include <cstdint>
#include <cstddef>

#define L_SEQ 2048
#define E_DIM 512
#define B_SZ 2
#define WIN 64
#define SCALE_QK 0.044194173824159216f  // 1/sqrt(512)

typedef __attribute__((ext_vector_type(8))) short short8;
typedef __attribute__((ext_vector_type(4))) float floatx4;

__device__ __forceinline__ unsigned short f2bf(float f) {
    unsigned int u = __float_as_uint(f);
    u += 0x7FFFu + ((u >> 16) & 1u);
    return (unsigned short)(u >> 16);
}

// ---------------- fp32 -> bf16 conversion of x, Wq, Wk, Wv ----------------
__global__ __launch_bounds__(256) void cvt_kernel(
    const float* __restrict__ x, const float* __restrict__ wq,
    const float* __restrict__ wk, const float* __restrict__ wv,
    unsigned short* __restrict__ xb, unsigned short* __restrict__ wb)
{
    long i = (long)blockIdx.x * 256 + threadIdx.x;   // 0 .. 720895
    const float* src;
    unsigned short* dst;
    long off;
    if (i < 524288) {
        src = x; dst = xb; off = i;
    } else {
        long j = i - 524288;
        int w = (int)(j >> 16);
        off = j & 65535;
        src = (w == 0) ? wq : ((w == 1) ? wk : wv);
        dst = wb + (long)w * 262144;
    }
    float4 f = ((const float4*)src)[off];
    ushort4 o;
    o.x = f2bf(f.x); o.y = f2bf(f.y); o.z = f2bf(f.z); o.w = f2bf(f.w);
    ((ushort4*)dst)[off] = o;
}

// ---------------- QKV projection: 64x64 tile, BK=64, reg double-buffer (R5/R7 winner) ----------------
// C[m,n] = sum_k X[m,k] W[n,k] + bias[n].  Outputs bf16, coalesced via LDS transpose.
// z==0 -> q[m][n], z==1 -> k[m][n], z==2 -> vT[n][m] (token-contiguous rows).
// grid (64,8,3) = 1536 blocks = 6 blocks/CU.
#define ALD 72   // LDS row stride (bf16): 36 dw -> 2-way conflicts only per 16-lane phase
__global__ __launch_bounds__(256) void qkv_gemm(
    const unsigned short* __restrict__ xb,   // 4096 x 512
    const unsigned short* __restrict__ wb,   // 3 x (512 x 512), (N,K)
    const float* __restrict__ bq, const float* __restrict__ bk, const float* __restrict__ bv,
    unsigned short* __restrict__ q, unsigned short* __restrict__ k,
    unsigned short* __restrict__ vt)
{
    __shared__ __align__(16) unsigned short As[64 * ALD];   // 9216 B (aliased by epilogue)
    __shared__ __align__(16) unsigned short Bs[64 * ALD];

    const int t = threadIdx.x;
    const int w = t >> 6, l = t & 63;
    const int m0 = blockIdx.x * 64, n0 = blockIdx.y * 64, z = blockIdx.z;
    const unsigned short* W = wb + (size_t)z * 262144;
    const float* bias = (z == 0) ? bq : ((z == 1) ? bk : bv);

    floatx4 acc[2][2] = {};
    const int wm = (w >> 1) * 32, wn = (w & 1) * 32;
    const int fr = l & 15, fq = l >> 4, fk = fq * 8;

    const int srow = t >> 2, scol = (t & 3) * 16;
    const unsigned short* gA = xb + (size_t)(m0 + srow) * 512 + scol;
    const unsigned short* gB = W  + (size_t)(n0 + srow) * 512 + scol;

    uint4 ra0 = *(const uint4*)(gA);     uint4 ra1 = *(const uint4*)(gA + 8);
    uint4 rb0 = *(const uint4*)(gB);     uint4 rb1 = *(const uint4*)(gB + 8);

    for (int it = 0; it < 8; it++) {
        *(uint4*)&As[srow * ALD + scol]     = ra0;
        *(uint4*)&As[srow * ALD + scol + 8] = ra1;
        *(uint4*)&Bs[srow * ALD + scol]     = rb0;
        *(uint4*)&Bs[srow * ALD + scol + 8] = rb1;
        __syncthreads();
        if (it < 7) {                       // prefetch next K-slice; overlaps compute below
            int kk = (it + 1) * 64;
            ra0 = *(const uint4*)(gA + kk); ra1 = *(const uint4*)(gA + kk + 8);
            rb0 = *(const uint4*)(gB + kk); rb1 = *(const uint4*)(gB + kk + 8);
        }
        short8 a[2][2], bf[2][2];
#pragma unroll
        for (int i = 0; i < 2; i++)
#pragma unroll
            for (int kh = 0; kh < 2; kh++)
                a[i][kh] = *(const short8*)&As[(wm + i * 16 + fr) * ALD + kh * 32 + fk];
#pragma unroll
        for (int j = 0; j < 2; j++)
#pragma unroll
            for (int kh = 0; kh < 2; kh++)
                bf[j][kh] = *(const short8*)&Bs[(wn + j * 16 + fr) * ALD + kh * 32 + fk];
#pragma unroll
        for (int kh = 0; kh < 2; kh++)
#pragma unroll
            for (int i = 0; i < 2; i++)
#pragma unroll
                for (int j = 0; j < 2; j++)
                    acc[i][j] = __builtin_amdgcn_mfma_f32_16x16x32_bf16(a[i][kh], bf[j][kh], acc[i][j], 0, 0, 0);
        __syncthreads();
    }

    // epilogue: frags (C/D: col=lane&15, row=(lane>>4)*4+reg) -> LDS tile -> coalesced stores
    unsigned short* Tl = As;   // 64 x ALD alias
    float bv_[2];
#pragma unroll
    for (int j = 0; j < 2; j++) bv_[j] = bias[n0 + wn + j * 16 + fr];

    if (z < 2) {
#pragma unroll
        for (int i = 0; i < 2; i++)
#pragma unroll
            for (int j = 0; j < 2; j++)
#pragma unroll
                for (int r = 0; r < 4; r++)
                    Tl[(wm + i * 16 + fq * 4 + r) * ALD + wn + j * 16 + fr] =
                        f2bf(acc[i][j][r] + bv_[j]);
    } else {
#pragma unroll
        for (int i = 0; i < 2; i++)
#pragma unroll
            for (int j = 0; j < 2; j++)
#pragma unroll
                for (int r = 0; r < 4; r++)
                    Tl[(wn + j * 16 + fr) * ALD + wm + i * 16 + fq * 4 + r] =
                        f2bf(acc[i][j][r] + bv_[j]);
    }
    __syncthreads();

    const int tr = t >> 2, tc = (t & 3) * 16;
    uint4 v0 = *(const uint4*)&Tl[tr * ALD + tc];
    uint4 v1 = *(const uint4*)&Tl[tr * ALD + tc + 8];
    if (z < 2) {
        unsigned short* out = (z == 0) ? q : k;
        *(uint4*)&out[(size_t)(m0 + tr) * 512 + n0 + tc]     = v0;
        *(uint4*)&out[(size_t)(m0 + tr) * 512 + n0 + tc + 8] = v1;
    } else {
        *(uint4*)&vt[(size_t)(n0 + tr) * 4096 + m0 + tc]     = v0;
        *(uint4*)&vt[(size_t)(n0 + tr) * 4096 + m0 + tc + 8] = v1;
    }
}

// ---------------- scores: S[16x16] per one-wave block, direct frag loads ----------------
// grid (128 Qtiles, 9 ntiles, 2 b), 64 threads. S fp32 [4096][160], cols 0..143 written.
__global__ __launch_bounds__(64) void scores_kernel(
    const unsigned short* __restrict__ qb, const unsigned short* __restrict__ kb,
    float* __restrict__ S)
{
    const int l = threadIdx.x;
    const int fr = l & 15, fq = l >> 4;
    const int Q0 = blockIdx.x * 16;
    const int nt = blockIdx.y;
    const int b  = blockIdx.z;
    const int R0 = Q0 - WIN;
    const int tok = R0 + nt * 16 + fr;
    const bool kvalid = (tok >= 0) && (tok < L_SEQ);

    const unsigned short* qrow = qb + (size_t)(b * L_SEQ + Q0 + fr) * 512 + fq * 8;
    const unsigned short* krow = kb + (size_t)(b * L_SEQ) * 512 + (size_t)tok * 512 + fq * 8;

    floatx4 acc = {};
#pragma unroll
    for (int ks = 0; ks < 16; ks++) {
        short8 a = *(const short8*)(qrow + ks * 32);
        short8 bfr = {};
        if (kvalid) bfr = *(const short8*)(krow + ks * 32);
        acc = __builtin_amdgcn_mfma_f32_16x16x32_bf16(a, bfr, acc, 0, 0, 0);
    }

    const int jg = nt * 16 + fr;
    float* Srow = S + (size_t)(b * L_SEQ + Q0) * 160 + jg;
#pragma unroll
    for (int r = 0; r < 4; r++) {
        int qq = fq * 4 + r;
        bool valid = (jg >= qq) && (jg <= qq + 128) && kvalid;
        Srow[(size_t)qq * 160] = valid ? acc[r] * SCALE_QK : -1e30f;
    }
}

// ---------------- pv (fused softmax): out[16q x 64e] per one-wave block ----------------
// grid (128 Qtiles, 8 e-quads, 2 b), 64 threads. vt B-frag loads issued BEFORE the
// softmax VALU block so global latency overlaps exp/reduce work (G7 ILP).
__global__ __launch_bounds__(64) void pv_kernel(
    const float* __restrict__ S, const unsigned short* __restrict__ vt,
    float* __restrict__ out)
{
    const int l = threadIdx.x;
    const int fr = l & 15, fq = l >> 4;
    const int Q0 = blockIdx.x * 16;
    const int EC = blockIdx.y * 64;
    const int b  = blockIdx.z;
    const int R0 = Q0 - WIN;

    // ---- issue S loads ----
    const float* Srow = S + (size_t)(b * L_SEQ + Q0 + fr) * 160 + fq * 8;
    float sv[5][8];
#pragma unroll
    for (int ks = 0; ks < 5; ks++) {
        float4 u0 = *(const float4*)(Srow + ks * 32);
        float4 u1 = *(const float4*)(Srow + ks * 32 + 4);
        sv[ks][0] = u0.x; sv[ks][1] = u0.y; sv[ks][2] = u0.z; sv[ks][3] = u0.w;
        sv[ks][4] = u1.x; sv[ks][5] = u1.y; sv[ks][6] = u1.z; sv[ks][7] = u1.w;
    }

    // ---- issue all vt B-frag loads up front (independent of softmax) ----
    short8 bfr[5][4];
#pragma unroll
    for (int ks = 0; ks < 5; ks++) {
        int tok0 = R0 + ks * 32 + fq * 8;                 // mod-8 aligned granule
        bool tv = (tok0 >= 0) && (tok0 < L_SEQ);
#pragma unroll
        for (int et = 0; et < 4; et++) {
            short8 v = {};
            if (tv) v = *(const short8*)&vt[(size_t)(EC + et * 16 + fr) * 4096 + b * L_SEQ + tok0];
            bfr[ks][et] = v;
        }
    }

    // ---- softmax on sv while vt loads are in flight ----
    if (fq >= 2) {                    // cols 144..159: unwritten pad
#pragma unroll
        for (int j = 0; j < 8; j++) sv[4][j] = -1e30f;
    }
    float m = -1e30f;
#pragma unroll
    for (int ks = 0; ks < 5; ks++)
#pragma unroll
        for (int j = 0; j < 8; j++) m = fmaxf(m, sv[ks][j]);
    m = fmaxf(m, __shfl_xor(m, 16));
    m = fmaxf(m, __shfl_xor(m, 32));
    float sum = 0.f;
#pragma unroll
    for (int ks = 0; ks < 5; ks++)
#pragma unroll
        for (int j = 0; j < 8; j++) { float e = __expf(sv[ks][j] - m); sv[ks][j] = e; sum += e; }
    sum += __shfl_xor(sum, 16);
    sum += __shfl_xor(sum, 32);
    float inv = 1.f / sum;

    short8 a[5];
#pragma unroll
    for (int ks = 0; ks < 5; ks++)
#pragma unroll
        for (int j = 0; j < 8; j++) a[ks][j] = (short)f2bf(sv[ks][j] * inv);

    floatx4 oa[4] = {};
#pragma unroll
    for (int ks = 0; ks < 5; ks++)
#pragma unroll
        for (int et = 0; et < 4; et++)
            oa[et] = __builtin_amdgcn_mfma_f32_16x16x32_bf16(a[ks], bfr[ks][et], oa[et], 0, 0, 0);

    float* op = out + (size_t)b * L_SEQ * E_DIM;
#pragma unroll
    for (int et = 0; et < 4; et++)
#pragma unroll
        for (int r = 0; r < 4; r++)
            op[(size_t)(Q0 + fq * 4 + r) * 512 + EC + et * 16 + fr] = oa[et][r];
}

// ---------------- launch ----------------
extern "C" void kernel_launch(void* const* d_in, const int* in_sizes, int n_in,
                              void* d_out, int out_size, void* d_ws, size_t ws_size,
                              hipStream_t stream)
{
    const float* x  = (const float*)d_in[0];
    const float* Wq = (const float*)d_in[1];
    const float* bq = (const float*)d_in[2];
    const float* Wk = (const float*)d_in[3];
    const float* bk = (const float*)d_in[4];
    const float* Wv = (const float*)d_in[5];
    const float* bv = (const float*)d_in[6];
    float* out = (float*)d_out;

    char* ws = (char*)d_ws;
    unsigned short* qb = (unsigned short*)(ws);                  // 4 MB bf16 q
    unsigned short* kb = (unsigned short*)(ws + 4194304);        // 4 MB bf16 k
    unsigned short* vt = (unsigned short*)(ws + 8388608);        // 4 MB bf16 v^T [e][tok]
    unsigned short* xb = (unsigned short*)(ws + 12582912);       // 4 MB bf16 x
    unsigned short* wb = (unsigned short*)(ws + 16777216);       // 1.5 MB bf16 W
    float*          S  = (float*)(ws + 18350080);                // 2.62 MB fp32 [4096][160]

    cvt_kernel<<<2816, 256, 0, stream>>>(x, Wq, Wk, Wv, xb, wb);
    qkv_gemm<<<dim3(64, 8, 3), 256, 0, stream>>>(xb, wb, bq, bk, bv, qb, kb, vt);
    scores_kernel<<<dim3(128, 9, 2), 64, 0, stream>>>(qb, kb, S);
    pv_kernel<<<dim3(128, 8, 2), 64, 0, stream>>>(S, vt, out);
}